// Round 1
// baseline (559.672 us; speedup 1.0000x reference)
//
#include <hip/hip_runtime.h>
#include <hip/hip_bf16.h>
#include <hip/hip_cooperative_groups.h>

namespace coop = cooperative_groups;

#define T_DIM 1024
#define B_DIM 16
#define H_DIM 1024
#define L_DIM 3
#define M_DIM (T_DIM * B_DIM)
#define N_DIM (3 * H_DIM)
#define K_DIM H_DIM
#define NC 64
#define CS 16

typedef __bf16 bf16x8 __attribute__((ext_vector_type(8)));
typedef __bf16 bf16x4 __attribute__((ext_vector_type(4)));
typedef _Float16 half4 __attribute__((ext_vector_type(4)));
typedef float f32x4 __attribute__((ext_vector_type(4)));

__device__ __forceinline__ __bf16 f2bf(float f) {
    return (__bf16)__float2bfloat16(f);
}

__device__ __forceinline__ void async_cp16(const void* g, void* lds) {
    __builtin_amdgcn_global_load_lds(
        (__attribute__((address_space(1))) void*)g,
        (__attribute__((address_space(3))) void*)lds, 16, 0, 0);
}

// ---------- fused prep: W transpose+cast (blocks 0..9215) + embed gather (rest) ----------
#define TW_BLOCKS (32 * 96 * 3)
__global__ void prep_kernel(const float* __restrict__ W, __bf16* __restrict__ Wt,
                            const int* __restrict__ x, const float4* __restrict__ emb,
                            __bf16* __restrict__ h) {
    if (blockIdx.x < TW_BLOCKS) {
        __shared__ __bf16 tile[32][33];
        const int blk = blockIdx.x;
        const int l = blk / 3072;
        const int r2 = blk % 3072;
        const int n0 = (r2 / 32) * 32, k0 = (r2 % 32) * 32;
        const int tx = threadIdx.x & 31, ty = threadIdx.x >> 5;
        const float* Wl = W + (size_t)l * K_DIM * N_DIM;
        __bf16* Wtl = Wt + (size_t)l * N_DIM * K_DIM;
#pragma unroll
        for (int q = 0; q < 4; q++) {
            int k = ty + q * 8;
            tile[k][tx] = f2bf(Wl[(size_t)(k0 + k) * N_DIM + n0 + tx]);
        }
        __syncthreads();
#pragma unroll
        for (int q = 0; q < 4; q++) {
            int n = ty + q * 8;
            Wtl[(size_t)(n0 + n) * K_DIM + k0 + tx] = tile[tx][n];
        }
    } else {
        int i = (blockIdx.x - TW_BLOCKS) * 256 + threadIdx.x;
        int row = i >> 8;
        int j = i & 255;
        int idx = x[row];
        float4 v = emb[(size_t)idx * 256 + j];
        __bf16* dst = h + (size_t)row * H_DIM + j * 4;
        dst[0] = f2bf(v.x); dst[1] = f2bf(v.y); dst[2] = f2bf(v.z); dst[3] = f2bf(v.w);
    }
}

// ---------- GEMM + bias + activation -> fp16 planar gates ----------
// 256x256 tile, 8 waves (2M x 4N, 128x64 out per wave), BK=64 as two K=32 half-regions.
// LDS ring: As/Bs = [buf(2)][kh(2)][256 rows][32 cols] bf16 = 64 KiB each (128 KiB total).
// 8-phase schedule, one 2-load global_load_lds stage per phase, counted vmcnt(8) at even
// phases (never 0 in the loop), setprio(1) around each 16-MFMA cluster.
// Swizzle: slot = chunk ^ ((row>>1)&3)  (inverse applied to the global source; LDS dest
// stays linear per global_load_lds constraint). 8-lane ds_read_b128 groups hit 8 distinct
// bank-quads -> conflict-free.
// Tail K-tiles (t+2,t+3 >= 16) wrap source address (&15) into already-freed regions so the
// vmcnt counts stay uniform.
__global__ __launch_bounds__(512, 2) void gemm_gates(
    const __bf16* __restrict__ A,
    const __bf16* __restrict__ Wt,
    const float* __restrict__ bias,
    _Float16* __restrict__ Gz, _Float16* __restrict__ Gf, _Float16* __restrict__ Go) {
    __shared__ __align__(16) __bf16 As[4 * 8192];
    __shared__ __align__(16) __bf16 Bs[4 * 8192];

    const int tid = threadIdx.x;
    const int lane = tid & 63, wid = tid >> 6;
    const int lm = lane & 15, kg = lane >> 4;
    const int waveM = wid >> 2, waveN = wid & 3;
    const int bm = blockIdx.x, bn = blockIdx.y;

    // staging offsets: lane-slot q*512+tid -> row = idx/4, slot = idx&3, chunk pre-swizzled
    const int sr = tid >> 2;                       // 0..127 (q=0); +128 for q=1
    const int sch = (tid & 3) ^ ((sr >> 1) & 3);   // source chunk for linear dest slot
    const int ga0 = sr * K_DIM + sch * 8;
    const int ga1 = (sr + 128) * K_DIM + sch * 8;
    const int lo0 = tid * 8;
    const int lo1 = (512 + tid) * 8;

    const __bf16* Abase = A + (size_t)(bm * 256) * K_DIM;
    const __bf16* Bbase = Wt + (size_t)(bn * 256) * K_DIM;

    // ds_read fragment offsets (within one [256][32] region)
    const int slot8 = (kg ^ ((lm >> 1) & 3)) * 8;
    const int a_off0 = (waveM * 128 + 0 * 16 + lm) * 32 + slot8;
    const int a_off1 = (waveM * 128 + 1 * 16 + lm) * 32 + slot8;
    const int a_off2 = (waveM * 128 + 2 * 16 + lm) * 32 + slot8;
    const int a_off3 = (waveM * 128 + 3 * 16 + lm) * 32 + slot8;
    const int b_off0 = (waveN * 64 + 0 * 16 + lm) * 32 + slot8;
    const int b_off1 = (waveN * 64 + 1 * 16 + lm) * 32 + slot8;
    const int b_off2 = (waveN * 64 + 2 * 16 + lm) * 32 + slot8;
    const int b_off3 = (waveN * 64 + 3 * 16 + lm) * 32 + slot8;

    f32x4 acc[8][4] = {};
    bf16x8 af0, af1, af2, af3;
    bf16x8 bf0 = {}, bf1 = {}, bf2 = {}, bf3 = {};

#define STAGE(ARR, GB, TILE, KH) { \
    const int tt_ = (TILE) & 15; \
    const int kc_ = tt_ * 64 + (KH) * 32; \
    __bf16* dst_ = (ARR) + ((tt_ & 1) * 2 + (KH)) * 8192; \
    async_cp16((GB) + kc_ + ga0, dst_ + lo0); \
    async_cp16((GB) + kc_ + ga1, dst_ + lo1); }

#define MF1(IA, J, AF, BF) \
    acc[IA][J] = __builtin_amdgcn_mfma_f32_16x16x32_bf16(AF, BF, acc[IA][J], 0, 0, 0);
#define MF4(IA, AF) MF1(IA, 0, AF, bf0) MF1(IA, 1, AF, bf1) MF1(IA, 2, AF, bf2) MF1(IA, 3, AF, bf3)

#define PHASE(BUF, KH, MQ, LB, STG, VM) { \
    const __bf16* rA_ = As + ((BUF) * 2 + (KH)) * 8192 + (MQ) * 2048; \
    if (LB) { \
        const __bf16* rB_ = Bs + ((BUF) * 2 + (KH)) * 8192; \
        bf0 = *(const bf16x8*)(rB_ + b_off0); \
        bf1 = *(const bf16x8*)(rB_ + b_off1); \
        bf2 = *(const bf16x8*)(rB_ + b_off2); \
        bf3 = *(const bf16x8*)(rB_ + b_off3); } \
    af0 = *(const bf16x8*)(rA_ + a_off0); \
    af1 = *(const bf16x8*)(rA_ + a_off1); \
    af2 = *(const bf16x8*)(rA_ + a_off2); \
    af3 = *(const bf16x8*)(rA_ + a_off3); \
    STG; \
    __builtin_amdgcn_s_barrier(); \
    asm volatile("s_waitcnt lgkmcnt(0)" ::: "memory"); \
    __builtin_amdgcn_sched_barrier(0); \
    __builtin_amdgcn_s_setprio(1); \
    MF4((MQ) * 4 + 0, af0) MF4((MQ) * 4 + 1, af1) MF4((MQ) * 4 + 2, af2) MF4((MQ) * 4 + 3, af3) \
    __builtin_amdgcn_s_setprio(0); \
    __builtin_amdgcn_sched_barrier(0); \
    if (VM) { asm volatile("s_waitcnt vmcnt(8)" ::: "memory"); } \
    __builtin_amdgcn_s_barrier(); }

    // prologue: (0,0) A,B ; (0,1) A,B ; (1,0) A,B  -> 12 loads, wait oldest 4 = region (0,0)
    STAGE(As, Abase, 0, 0) STAGE(Bs, Bbase, 0, 0)
    STAGE(As, Abase, 0, 1) STAGE(Bs, Bbase, 0, 1)
    STAGE(As, Abase, 1, 0) STAGE(Bs, Bbase, 1, 0)
    asm volatile("s_waitcnt vmcnt(8)" ::: "memory");
    __builtin_amdgcn_s_barrier();

#pragma unroll 1
    for (int t = 0; t < 16; t += 2) {
        PHASE(0, 0, 0, 1, STAGE(As, Abase, t + 1, 1), 0)
        PHASE(0, 0, 1, 0, STAGE(Bs, Bbase, t + 1, 1), 1)
        PHASE(0, 1, 0, 1, STAGE(As, Abase, t + 2, 0), 0)
        PHASE(0, 1, 1, 0, STAGE(Bs, Bbase, t + 2, 0), 1)
        PHASE(1, 0, 0, 1, STAGE(As, Abase, t + 2, 1), 0)
        PHASE(1, 0, 1, 0, STAGE(Bs, Bbase, t + 2, 1), 1)
        PHASE(1, 1, 0, 1, STAGE(As, Abase, t + 3, 0), 0)
        PHASE(1, 1, 1, 0, STAGE(Bs, Bbase, t + 3, 0), 1)
    }
    asm volatile("s_waitcnt vmcnt(0)" ::: "memory");

#undef PHASE
#undef MF4
#undef MF1
#undef STAGE

    // epilogue; plane is block-uniform (bn quadrant covers 256 cols inside one 1024-col plane)
    const int plane = bn >> 2;
    _Float16* __restrict__ P = (plane == 0) ? Gz : (plane == 1) ? Gf : Go;
    const int colbase = (bn & 3) * 256 + waveN * 64;
    const int nb = bn * 256 + waveN * 64;
#pragma unroll
    for (int mq = 0; mq < 2; mq++) {
#pragma unroll
        for (int i = 0; i < 4; i++) {
#pragma unroll
            for (int j = 0; j < 4; j++) {
                int col = colbase + j * 16 + lm;
                float bv = bias[nb + j * 16 + lm];
#pragma unroll
                for (int r = 0; r < 4; r++) {
                    int mrow = bm * 256 + waveM * 128 + mq * 64 + i * 16 + kg * 4 + r;
                    float g = acc[mq * 4 + i][j][r] + bv;
                    float val;
                    if (plane == 0) {
                        // tanh(g) = sign(g) * (1 - 2e/(1+e)), e = exp(-2|g|) <= 1
                        float e = __expf(-2.0f * fabsf(g));
                        float rc = __builtin_amdgcn_rcpf(1.0f + e);
                        val = copysignf(fmaf(-2.0f * e, rc, 1.0f), g);
                    } else {
                        float e = __expf(-g);
                        val = __builtin_amdgcn_rcpf(1.0f + e);
                    }
                    P[(size_t)mrow * H_DIM + col] = (_Float16)val;
                }
            }
        }
    }
}

// ---------- coop fused scan: pass1 (regs kept) + grid.sync + redundant fold + pass3 ----------
// grid MUST be 1024 blocks x 256 threads, all co-resident (guarded by occupancy query).
__global__ __launch_bounds__(256, 4) void scan_fused(
    const _Float16* __restrict__ Gz, const _Float16* __restrict__ Gf,
    const _Float16* __restrict__ Go,
    float* __restrict__ cA, float* __restrict__ cM,
    __bf16* __restrict__ hdst, float* __restrict__ fdst, int is_last) {
    int tidg = blockIdx.x * 256 + threadIdx.x;   // 262144
    int ci = tidg >> 12;                         // chunk 0..63
    int chg = tidg & 4095;                       // channel-group of 4
    size_t base = (size_t)(ci * CS) * 16384 + (size_t)chg * 4;

    // phase 1: local chunk aggregates; keep z,f in registers (16 x 2 x half4 = 64 VGPRs)
    half4 zs[CS], fs[CS];
    f32x4 Aacc = {0.f, 0.f, 0.f, 0.f};
    f32x4 Macc = {1.f, 1.f, 1.f, 1.f};
    {
        size_t p = base;
#pragma unroll
        for (int s = 0; s < CS; s++) {
            zs[s] = *(const half4*)(Gz + p);
            fs[s] = *(const half4*)(Gf + p);
#pragma unroll
            for (int k = 0; k < 4; k++) {
                float fk = (float)fs[s][k], zk = (float)zs[s][k];
                Aacc[k] = fk * zk + (1.f - fk) * Aacc[k];
                Macc[k] = (1.f - fk) * Macc[k];
            }
            p += 16384;
        }
    }
    size_t idx = (size_t)ci * 16384 + (size_t)chg * 4;
    *(f32x4*)(cA + idx) = Aacc;
    *(f32x4*)(cM + idx) = Macc;

    __threadfence();                 // device-scope release of cA/cM
    coop::this_grid().sync();

    // phase 2: fold prior chunks' aggregates (cA/cM L2-hot, 8 MB)
    f32x4 c = {0.f, 0.f, 0.f, 0.f};
    for (int cj = 0; cj < ci; cj++) {
        size_t jdx = (size_t)cj * 16384 + (size_t)chg * 4;
        f32x4 a = *(const f32x4*)(cA + jdx);
        f32x4 m = *(const f32x4*)(cM + jdx);
#pragma unroll
        for (int k = 0; k < 4; k++) c[k] = a[k] + m[k] * c[k];
    }

    // phase 3: rescan from registers + output gate (only o is loaded)
    size_t p = base;
#pragma unroll
    for (int s = 0; s < CS; s++) {
        int t = ci * CS + s;
        half4 o = *(const half4*)(Go + p);
        f32x4 val;
#pragma unroll
        for (int k = 0; k < 4; k++) {
            float fk = (float)fs[s][k];
            c[k] = fk * (float)zs[s][k] + (1.f - fk) * c[k];
            val[k] = (float)o[k] * c[k];
        }
        if (is_last) {
            if (t < T_DIM - 1)
                *(f32x4*)(fdst + p) = val;
        } else {
            bf16x4 hv;
#pragma unroll
            for (int k = 0; k < 4; k++) hv[k] = f2bf(val[k]);
            *(bf16x4*)(hdst + p) = hv;
        }
        p += 16384;
    }
}

// ---------- fallback pass 1: per-chunk affine aggregates ----------
__global__ __launch_bounds__(256, 8) void scan_pass1(
    const _Float16* __restrict__ Gz, const _Float16* __restrict__ Gf,
    float* __restrict__ cA, float* __restrict__ cM) {
    int tidg = blockIdx.x * 256 + threadIdx.x;   // 262144
    int ci = tidg >> 12;
    int chg = tidg & 4095;
    size_t base = (size_t)(ci * CS) * 16384 + (size_t)chg * 4;
    f32x4 Aacc = {0.f, 0.f, 0.f, 0.f};
    f32x4 Macc = {1.f, 1.f, 1.f, 1.f};
#pragma unroll
    for (int s = 0; s < CS; s++) {
        half4 z = *(const half4*)(Gz + base);
        half4 f = *(const half4*)(Gf + base);
#pragma unroll
        for (int k = 0; k < 4; k++) {
            float fk = (float)f[k], zk = (float)z[k];
            Aacc[k] = fk * zk + (1.f - fk) * Aacc[k];
            Macc[k] = (1.f - fk) * Macc[k];
        }
        base += 16384;
    }
    size_t idx = (size_t)ci * 16384 + (size_t)chg * 4;
    *(f32x4*)(cA + idx) = Aacc;
    *(f32x4*)(cM + idx) = Macc;
}

// ---------- fallback pass 2+3: redundant chunk-prefix fold + rescan + o-gate ----------
__global__ __launch_bounds__(256, 8) void scan_pass23(
    const _Float16* __restrict__ Gz, const _Float16* __restrict__ Gf,
    const _Float16* __restrict__ Go,
    const float* __restrict__ cA, const float* __restrict__ cM,
    __bf16* __restrict__ hdst, float* __restrict__ fdst, int is_last) {
    int tidg = blockIdx.x * 256 + threadIdx.x;   // 262144
    int ci = tidg >> 12;                         // uniform per block
    int chg = tidg & 4095;
    // fold prior chunks' aggregates (same order as coop path -> bit-identical)
    f32x4 c = {0.f, 0.f, 0.f, 0.f};
    for (int cj = 0; cj < ci; cj++) {
        size_t jdx = (size_t)cj * 16384 + (size_t)chg * 4;
        f32x4 a = *(const f32x4*)(cA + jdx);
        f32x4 m = *(const f32x4*)(cM + jdx);
#pragma unroll
        for (int k = 0; k < 4; k++) c[k] = a[k] + m[k] * c[k];
    }
    size_t p = (size_t)(ci * CS) * 16384 + (size_t)chg * 4;
#pragma unroll
    for (int s = 0; s < CS; s++) {
        int t = ci * CS + s;
        half4 z = *(const half4*)(Gz + p);
        half4 f = *(const half4*)(Gf + p);
        half4 o = *(const half4*)(Go + p);
        f32x4 val;
#pragma unroll
        for (int k = 0; k < 4; k++) {
            float fk = (float)f[k];
            c[k] = fk * (float)z[k] + (1.f - fk) * c[k];
            val[k] = (float)o[k] * c[k];
        }
        if (is_last) {
            if (t < T_DIM - 1)
                *(f32x4*)(fdst + p) = val;
        } else {
            bf16x4 hv;
#pragma unroll
            for (int k = 0; k < 4; k++) hv[k] = f2bf(val[k]);
            *(bf16x4*)(hdst + p) = hv;
        }
        p += 16384;
    }
}

extern "C" void kernel_launch(void* const* d_in, const int* in_sizes, int n_in,
                              void* d_out, int out_size, void* d_ws, size_t ws_size,
                              hipStream_t stream) {
    const int* x = (const int*)d_in[0];
    const float* emb = (const float*)d_in[1];
    const float* W = (const float*)d_in[2];
    const float* b = (const float*)d_in[3];
    float* out = (float*)d_out;

    char* ws = (char*)d_ws;
    size_t need = (size_t)L_DIM * N_DIM * K_DIM * 2
                + (size_t)M_DIM * H_DIM * 2
                + 3ull * M_DIM * H_DIM * 2
                + 2ull * NC * 16384 * 4;
    if (ws_size < need) return;

    __bf16* Wt = (__bf16*)ws;     ws += (size_t)L_DIM * N_DIM * K_DIM * 2;
    __bf16* hbuf = (__bf16*)ws;   ws += (size_t)M_DIM * H_DIM * 2;
    _Float16* Gz = (_Float16*)ws; ws += (size_t)M_DIM * H_DIM * 2;
    _Float16* Gf = (_Float16*)ws; ws += (size_t)M_DIM * H_DIM * 2;
    _Float16* Go = (_Float16*)ws; ws += (size_t)M_DIM * H_DIM * 2;
    float* cA = (float*)ws;       ws += (size_t)NC * 16384 * 4;
    float* cM = (float*)ws;

    // host-side, capture-safe, deterministic: can 1024 coop blocks be co-resident?
    int blocksPerCU = 0;
    hipError_t qe = hipOccupancyMaxActiveBlocksPerMultiprocessor(
        &blocksPerCU, (const void*)scan_fused, 256, 0);
    const bool use_coop = (qe == hipSuccess && blocksPerCU >= 4);

    prep_kernel<<<TW_BLOCKS + 16384, 256, 0, stream>>>(W, Wt, x, (const float4*)emb, hbuf);

    for (int l = 0; l < L_DIM; l++) {
        gemm_gates<<<dim3(M_DIM / 256, N_DIM / 256), 512, 0, stream>>>(
            hbuf, Wt + (size_t)l * N_DIM * K_DIM, b + (size_t)l * N_DIM, Gz, Gf, Go);
        int last = (l == L_DIM - 1);

        bool launched = false;
        if (use_coop) {
            const _Float16* aGz = Gz; const _Float16* aGf = Gf; const _Float16* aGo = Go;
            float* acA = cA; float* acM = cM;
            __bf16* ah = hbuf; float* af = out;
            void* args[] = {(void*)&aGz, (void*)&aGf, (void*)&aGo,
                            (void*)&acA, (void*)&acM, (void*)&ah, (void*)&af, (void*)&last};
            hipError_t e = hipLaunchCooperativeKernel((const void*)scan_fused,
                                                      dim3(1024), dim3(256), args, 0, stream);
            launched = (e == hipSuccess);
        }
        if (!launched) {
            scan_pass1<<<1024, 256, 0, stream>>>(Gz, Gf, cA, cM);
            scan_pass23<<<1024, 256, 0, stream>>>(Gz, Gf, Go, cA, cM, hbuf, out, last);
        }
    }
}